// Round 1
// baseline (710.613 us; speedup 1.0000x reference)
//
#include <hip/hip_runtime.h>
#include <stdint.h>

constexpr int SEQ  = 2048;
constexpr int DIM  = 1024;
constexpr int NH   = 16;
constexpr int HDIM = 64;
constexpr int TOPK = 16;

typedef unsigned short bf16_t;
typedef __attribute__((ext_vector_type(8))) short bf16x8;
typedef __attribute__((ext_vector_type(4))) float f32x4;

__device__ __forceinline__ float bf2f(bf16_t b) {
  return __uint_as_float(((unsigned)b) << 16);
}
__device__ __forceinline__ bf16_t f2bf(float f) {
  unsigned u = __float_as_uint(f);
  unsigned r = u + 0x7fffu + ((u >> 16) & 1u);
  return (bf16_t)(r >> 16);
}
__device__ __forceinline__ f32x4 zero4() {
  f32x4 z; z[0] = 0.f; z[1] = 0.f; z[2] = 0.f; z[3] = 0.f; return z;
}
__device__ __forceinline__ void gload_lds16(const bf16_t* g, bf16_t* l) {
  __builtin_amdgcn_global_load_lds(
      (const __attribute__((address_space(1))) void*)g,
      (__attribute__((address_space(3))) void*)l, 16, 0, 0);
}

// ---------------- cast x (f32 -> bf16) ----------------
__global__ void cast_x_kernel(const float* __restrict__ x, bf16_t* __restrict__ xb) {
  int i = (blockIdx.x * 256 + threadIdx.x) * 4;
  float4 v = *reinterpret_cast<const float4*>(x + i);
  ushort4 o;
  o.x = f2bf(v.x); o.y = f2bf(v.y); o.z = f2bf(v.z); o.w = f2bf(v.w);
  *reinterpret_cast<ushort4*>(xb + i) = o;
}

// ---------------- transpose + cast weight: WT[n][k] = bf16(W[k][n]) ----------------
__global__ void transpose_cast(const float* __restrict__ W, bf16_t* __restrict__ WT) {
  __shared__ float tile[32][33];
  int tx = threadIdx.x, ty = threadIdx.y;
  int bx = blockIdx.x * 32, by = blockIdx.y * 32;
#pragma unroll
  for (int i = 0; i < 4; ++i)
    tile[ty + i * 8][tx] = W[(by + ty + i * 8) * DIM + bx + tx];
  __syncthreads();
#pragma unroll
  for (int i = 0; i < 4; ++i)
    WT[(bx + ty + i * 8) * DIM + by + tx] = f2bf(tile[tx][ty + i * 8]);
}

// ---------------- GEMM: C[M=2048][N=1024] = A[2048][1024] @ Bt[1024][1024]^T + bias ----------------
// BM=128 BN=64 BK=64, 256 threads = 4 waves (2x2), wave tile 64x32.
template <int OUT_F32>
__global__ __launch_bounds__(256) void gemm_bt(const bf16_t* __restrict__ A,
                                               const bf16_t* __restrict__ Bt,
                                               const float* __restrict__ bias,
                                               void* __restrict__ Cv) {
  __shared__ __align__(16) bf16_t As[128 * 64];
  __shared__ __align__(16) bf16_t Bs[64 * 64];
  const int t = threadIdx.x;
  const int bm0 = blockIdx.y * 128, bn0 = blockIdx.x * 64;
  const int w = t >> 6, lane = t & 63, lr = lane & 15, lg = lane >> 4;
  const int wm = w >> 1, wn = w & 1;
  const int srow = t >> 3, scol = (t & 7) * 8;

  f32x4 acc[4][2];
#pragma unroll
  for (int m = 0; m < 4; ++m)
#pragma unroll
    for (int n = 0; n < 2; ++n) acc[m][n] = zero4();

  for (int kt = 0; kt < 16; ++kt) {
    __syncthreads();
#pragma unroll
    for (int i = 0; i < 4; ++i)
      gload_lds16(A + (bm0 + i * 32 + srow) * DIM + kt * 64 + scol,
                  &As[(i * 32 + srow) * 64 + scol]);
#pragma unroll
    for (int i = 0; i < 2; ++i)
      gload_lds16(Bt + (bn0 + i * 32 + srow) * DIM + kt * 64 + scol,
                  &Bs[(i * 32 + srow) * 64 + scol]);
    __syncthreads();

    bf16x8 a[4][2], b[2][2];
#pragma unroll
    for (int m = 0; m < 4; ++m)
#pragma unroll
      for (int kk = 0; kk < 2; ++kk)
        a[m][kk] = *reinterpret_cast<const bf16x8*>(
            &As[(wm * 64 + m * 16 + lr) * 64 + kk * 32 + lg * 8]);
#pragma unroll
    for (int n = 0; n < 2; ++n)
#pragma unroll
      for (int kk = 0; kk < 2; ++kk)
        b[n][kk] = *reinterpret_cast<const bf16x8*>(
            &Bs[(wn * 32 + n * 16 + lr) * 64 + kk * 32 + lg * 8]);
#pragma unroll
    for (int m = 0; m < 4; ++m)
#pragma unroll
      for (int n = 0; n < 2; ++n)
#pragma unroll
        for (int kk = 0; kk < 2; ++kk)
          acc[m][n] = __builtin_amdgcn_mfma_f32_16x16x32_bf16(a[m][kk], b[n][kk],
                                                              acc[m][n], 0, 0, 0);
  }

#pragma unroll
  for (int m = 0; m < 4; ++m)
#pragma unroll
    for (int n = 0; n < 2; ++n) {
      int col = bn0 + wn * 32 + n * 16 + lr;
      float bv = bias[col];
#pragma unroll
      for (int r = 0; r < 4; ++r) {
        int row = bm0 + wm * 64 + m * 16 + lg * 4 + r;
        float val = acc[m][n][r] + bv;
        if (OUT_F32)
          reinterpret_cast<float*>(Cv)[row * DIM + col] = val;
        else
          reinterpret_cast<bf16_t*>(Cv)[row * DIM + col] = f2bf(val);
      }
    }
}

// ---------------- column sums of V: sumv[d] = sum_s v[s][d] ----------------
__global__ void sumv_kernel(const bf16_t* __restrict__ v, float* __restrict__ sumv) {
  int chunk = blockIdx.x >> 2;                 // 16 chunks of 128 rows
  int d = (blockIdx.x & 3) * 256 + threadIdx.x;
  float acc = 0.f;
  int s0 = chunk * 128;
  for (int s = s0; s < s0 + 128; ++s) acc += bf2f(v[s * DIM + d]);
  atomicAdd(&sumv[d], acc);
}

// ---------------- fused scores + topk + sparse-softmax + weighted V gather ----------------
// block: 256 threads (4 waves); one head x 128 q-rows. Loop over 32 K-chunks of 64.
__global__ __launch_bounds__(256) void attn_kernel(const bf16_t* __restrict__ q,
                                                   const bf16_t* __restrict__ k,
                                                   const bf16_t* __restrict__ v,
                                                   const float* __restrict__ sumv,
                                                   bf16_t* __restrict__ op) {
  __shared__ __align__(16) bf16_t Qs[128 * 64];
  __shared__ __align__(16) bf16_t Ks[64 * 64];
  __shared__ float Sc[128 * 65];  // pad-65: scan reads are 2-way (free) bank pattern

  const int t = threadIdx.x;
  const int qt = blockIdx.x, h = blockIdx.y;
  const int w = t >> 6, lane = t & 63, lr = lane & 15, lg = lane >> 4;
  const int srow = t >> 3, scol = (t & 7) * 8;
  const int scanrow = t >> 1, scanhalf = t & 1;

  // stage Q tile [128][64] once
#pragma unroll
  for (int i = 0; i < 4; ++i)
    gload_lds16(q + (qt * 128 + i * 32 + srow) * DIM + h * HDIM + scol,
                &Qs[(i * 32 + srow) * 64 + scol]);

  float tv[TOPK];
  int ti[TOPK];
#pragma unroll
  for (int j = 0; j < TOPK; ++j) { tv[j] = -1e30f; ti[j] = 0; }
  float minv = -1e30f;

  for (int kc = 0; kc < 32; ++kc) {
    // stage K chunk [64][64]
#pragma unroll
    for (int i = 0; i < 2; ++i)
      gload_lds16(k + (kc * 64 + i * 32 + srow) * DIM + h * HDIM + scol,
                  &Ks[(i * 32 + srow) * 64 + scol]);
    __syncthreads();  // staging done (drains vmcnt); also orders prev scan vs Sc overwrite

    // scores: wave w covers q-rows [w*32, w*32+32)
    f32x4 sacc[2][4];
#pragma unroll
    for (int m = 0; m < 2; ++m)
#pragma unroll
      for (int n = 0; n < 4; ++n) sacc[m][n] = zero4();

    bf16x8 aq[2][2], bk_[4][2];
#pragma unroll
    for (int m = 0; m < 2; ++m)
#pragma unroll
      for (int kk = 0; kk < 2; ++kk)
        aq[m][kk] = *reinterpret_cast<const bf16x8*>(
            &Qs[(w * 32 + m * 16 + lr) * 64 + kk * 32 + lg * 8]);
#pragma unroll
    for (int n = 0; n < 4; ++n)
#pragma unroll
      for (int kk = 0; kk < 2; ++kk)
        bk_[n][kk] = *reinterpret_cast<const bf16x8*>(
            &Ks[(n * 16 + lr) * 64 + kk * 32 + lg * 8]);
#pragma unroll
    for (int m = 0; m < 2; ++m)
#pragma unroll
      for (int n = 0; n < 4; ++n)
#pragma unroll
        for (int kk = 0; kk < 2; ++kk)
          sacc[m][n] = __builtin_amdgcn_mfma_f32_16x16x32_bf16(aq[m][kk], bk_[n][kk],
                                                               sacc[m][n], 0, 0, 0);
#pragma unroll
    for (int m = 0; m < 2; ++m)
#pragma unroll
      for (int n = 0; n < 4; ++n)
#pragma unroll
        for (int r = 0; r < 4; ++r)
          Sc[(w * 32 + m * 16 + lg * 4 + r) * 65 + n * 16 + lr] =
              sacc[m][n][r] * 0.125f;  // 1/sqrt(64)
    __syncthreads();

    // topk scan: 2 threads per row, 32 candidates each
    const int kbase = kc * 64 + scanhalf * 32;
    for (int c = 0; c < 32; ++c) {
      float sv = Sc[scanrow * 65 + scanhalf * 32 + c];
      if (sv > minv) {
        bool done = false;
#pragma unroll
        for (int j = 0; j < TOPK; ++j)
          if (!done && tv[j] == minv) { tv[j] = sv; ti[j] = kbase + c; done = true; }
        minv = tv[0];
#pragma unroll
        for (int j = 1; j < TOPK; ++j) minv = fminf(minv, tv[j]);
      }
    }
  }

  __syncthreads();
  // dump per-thread lists: vals -> slots[0..31], idx-bits -> slots[32..63]
#pragma unroll
  for (int j = 0; j < TOPK; ++j) {
    Sc[scanrow * 65 + scanhalf * 16 + j] = tv[j];
    Sc[scanrow * 65 + 32 + scanhalf * 16 + j] = __int_as_float(ti[j]);
  }
  __syncthreads();

  float* fbuf = reinterpret_cast<float*>(Qs);  // [128][32]: w[16] + idxbits[16]
  float* zbuf = reinterpret_cast<float*>(Ks);  // [128]: Z

  // merge 2x16 -> top16, compute Z and weights (one thread per row)
  if (t < 128) {
    const int row = t;
    float Zexp = 0.f;
    for (int ssel = 0; ssel < TOPK; ++ssel) {
      float best = -1e30f;
      int bpos = 0;
      for (int c = 0; c < 32; ++c) {
        float vv = Sc[row * 65 + c];
        if (vv > best) { best = vv; bpos = c; }
      }
      Sc[row * 65 + bpos] = -1e30f;
      float e = expf(best);
      Zexp += e;
      fbuf[row * 32 + ssel] = e - 1.f;
      fbuf[row * 32 + 16 + ssel] = Sc[row * 65 + 32 + bpos];
    }
    zbuf[row] = 2032.f + Zexp;  // (2048-16) ones + topk exps
  }
  __syncthreads();

  // output: out_pre[row][d] = (sumv[d] + sum_j w_j * v[idx_j][d]) / Z
  {
    const int row = t >> 1, half = t & 1;
    const int dbase = h * HDIM + half * 32;
    float oacc[32];
#pragma unroll
    for (int c = 0; c < 32; ++c) oacc[c] = sumv[dbase + c];
    float invZ = 1.f / zbuf[row];
#pragma unroll
    for (int j = 0; j < TOPK; ++j) {
      float wj = fbuf[row * 32 + j];
      int kidx = __float_as_int(fbuf[row * 32 + 16 + j]);
      const bf16x8* vp = reinterpret_cast<const bf16x8*>(v + kidx * DIM + dbase);
#pragma unroll
      for (int u8 = 0; u8 < 4; ++u8) {
        bf16x8 vv = vp[u8];
#pragma unroll
        for (int e = 0; e < 8; ++e) oacc[u8 * 8 + e] += wj * bf2f((bf16_t)vv[e]);
      }
    }
    bf16_t* orow = op + (qt * 128 + row) * DIM + dbase;
#pragma unroll
    for (int c = 0; c < 32; ++c) orow[c] = f2bf(oacc[c] * invZ);
  }
}

extern "C" void kernel_launch(void* const* d_in, const int* in_sizes, int n_in,
                              void* d_out, int out_size, void* d_ws, size_t ws_size,
                              hipStream_t stream) {
  const float* x  = (const float*)d_in[0];
  const float* Wq = (const float*)d_in[1];
  const float* bq = (const float*)d_in[2];
  const float* Wk = (const float*)d_in[3];
  const float* bk = (const float*)d_in[4];
  const float* Wv = (const float*)d_in[5];
  const float* bv = (const float*)d_in[6];
  const float* Wo = (const float*)d_in[7];
  const float* bo = (const float*)d_in[8];
  float* out = (float*)d_out;

  char* ws = (char*)d_ws;
  bf16_t* xb   = (bf16_t*)(ws + (size_t)(0)  * (1 << 20));
  bf16_t* WqT  = (bf16_t*)(ws + (size_t)(4)  * (1 << 20));
  bf16_t* WkT  = (bf16_t*)(ws + (size_t)(6)  * (1 << 20));
  bf16_t* WvT  = (bf16_t*)(ws + (size_t)(8)  * (1 << 20));
  bf16_t* WoT  = (bf16_t*)(ws + (size_t)(10) * (1 << 20));
  bf16_t* qb   = (bf16_t*)(ws + (size_t)(12) * (1 << 20));
  bf16_t* kb   = (bf16_t*)(ws + (size_t)(16) * (1 << 20));
  bf16_t* vb   = (bf16_t*)(ws + (size_t)(20) * (1 << 20));
  bf16_t* opb  = (bf16_t*)(ws + (size_t)(24) * (1 << 20));
  float*  sumv = (float*) (ws + (size_t)(28) * (1 << 20));

  cast_x_kernel<<<2048, 256, 0, stream>>>(x, xb);
  dim3 tb(32, 8), tg(32, 32);
  transpose_cast<<<tg, tb, 0, stream>>>(Wq, WqT);
  transpose_cast<<<tg, tb, 0, stream>>>(Wk, WkT);
  transpose_cast<<<tg, tb, 0, stream>>>(Wv, WvT);
  transpose_cast<<<tg, tb, 0, stream>>>(Wo, WoT);

  dim3 gg(DIM / 64, SEQ / 128);  // (16, 16)
  gemm_bt<0><<<gg, 256, 0, stream>>>(xb, WqT, bq, qb);
  gemm_bt<0><<<gg, 256, 0, stream>>>(xb, WkT, bk, kb);
  gemm_bt<0><<<gg, 256, 0, stream>>>(xb, WvT, bv, vb);

  hipMemsetAsync(sumv, 0, DIM * sizeof(float), stream);
  sumv_kernel<<<64, 256, 0, stream>>>(vb, sumv);

  attn_kernel<<<dim3(SEQ / 128, NH), 256, 0, stream>>>(qb, kb, vb, sumv, opb);

  gemm_bt<1><<<gg, 256, 0, stream>>>(opb, WoT, bo, out);
}

// Round 2
// 311.351 us; speedup vs baseline: 2.2824x; 2.2824x over previous
//
#include <hip/hip_runtime.h>
#include <stdint.h>

constexpr int SEQ  = 2048;
constexpr int DIM  = 1024;
constexpr int NH   = 16;
constexpr int HDIM = 64;
constexpr int TOPK = 16;
constexpr int CAP  = 96;   // candidate buffer per row (expected fill ~32)
constexpr int CST  = 97;   // padded stride: bank = (row + p) % 32 -> conflict-free scans

typedef unsigned short bf16_t;
typedef __attribute__((ext_vector_type(8))) short bf16x8;
typedef __attribute__((ext_vector_type(4))) float f32x4;

__device__ __forceinline__ float bf2f(bf16_t b) {
  return __uint_as_float(((unsigned)b) << 16);
}
__device__ __forceinline__ bf16_t f2bf(float f) {
  unsigned u = __float_as_uint(f);
  unsigned r = u + 0x7fffu + ((u >> 16) & 1u);
  return (bf16_t)(r >> 16);
}
__device__ __forceinline__ f32x4 zero4() {
  f32x4 z; z[0] = 0.f; z[1] = 0.f; z[2] = 0.f; z[3] = 0.f; return z;
}
__device__ __forceinline__ void gload_lds16(const bf16_t* g, bf16_t* l) {
  __builtin_amdgcn_global_load_lds(
      (const __attribute__((address_space(1))) void*)g,
      (__attribute__((address_space(3))) void*)l, 16, 0, 0);
}

// ---------------- cast x (f32 -> bf16) ----------------
__global__ void cast_x_kernel(const float* __restrict__ x, bf16_t* __restrict__ xb) {
  int i = (blockIdx.x * 256 + threadIdx.x) * 4;
  float4 v = *reinterpret_cast<const float4*>(x + i);
  ushort4 o;
  o.x = f2bf(v.x); o.y = f2bf(v.y); o.z = f2bf(v.z); o.w = f2bf(v.w);
  *reinterpret_cast<ushort4*>(xb + i) = o;
}

// ---------------- transpose + cast 4 weights in one launch ----------------
__global__ void transpose_cast4(const float* __restrict__ W0, const float* __restrict__ W1,
                                const float* __restrict__ W2, const float* __restrict__ W3,
                                bf16_t* __restrict__ T0, bf16_t* __restrict__ T1,
                                bf16_t* __restrict__ T2, bf16_t* __restrict__ T3) {
  const int z = blockIdx.z;
  const float* W = (z == 0) ? W0 : (z == 1) ? W1 : (z == 2) ? W2 : W3;
  bf16_t* WT = (z == 0) ? T0 : (z == 1) ? T1 : (z == 2) ? T2 : T3;
  __shared__ float tile[32][33];
  int tx = threadIdx.x, ty = threadIdx.y;
  int bx = blockIdx.x * 32, by = blockIdx.y * 32;
#pragma unroll
  for (int i = 0; i < 4; ++i)
    tile[ty + i * 8][tx] = W[(by + ty + i * 8) * DIM + bx + tx];
  __syncthreads();
#pragma unroll
  for (int i = 0; i < 4; ++i)
    WT[(bx + ty + i * 8) * DIM + by + tx] = f2bf(tile[tx][ty + i * 8]);
}

// ---------------- GEMM 64x64 tile, BK=64, dbuf single-barrier ----------------
// C[M=2048][N] = A[2048][1024] @ Bt[N][1024]^T + bias.  4 waves, wave tile 32x32.
// grid.x = nmat*16 (which = blockIdx.x>>4 selects Bt/bias/out), grid.y = 32.
template <int OUT_F32>
__global__ __launch_bounds__(256) void gemm64(const bf16_t* __restrict__ A,
                                              const bf16_t* __restrict__ B0,
                                              const bf16_t* __restrict__ B1,
                                              const bf16_t* __restrict__ B2,
                                              const float* __restrict__ c0,
                                              const float* __restrict__ c1,
                                              const float* __restrict__ c2,
                                              void* __restrict__ o0,
                                              void* __restrict__ o1,
                                              void* __restrict__ o2) {
  __shared__ __align__(16) bf16_t As[2][64 * 64];
  __shared__ __align__(16) bf16_t Bs[2][64 * 64];
  const int t = threadIdx.x;
  const int which = blockIdx.x >> 4;
  const bf16_t* Bt = (which == 0) ? B0 : (which == 1) ? B1 : B2;
  const float* bias = (which == 0) ? c0 : (which == 1) ? c1 : c2;
  void* out = (which == 0) ? o0 : (which == 1) ? o1 : o2;
  const int bm0 = blockIdx.y * 64, bn0 = (blockIdx.x & 15) * 64;
  const int w = t >> 6, lane = t & 63, lr = lane & 15, lg = lane >> 4;
  const int wm = w >> 1, wn = w & 1;
  const int srow = t >> 3, scol = (t & 7) * 8;

  f32x4 acc[2][2];
#pragma unroll
  for (int m = 0; m < 2; ++m)
#pragma unroll
    for (int n = 0; n < 2; ++n) acc[m][n] = zero4();

#pragma unroll
  for (int i = 0; i < 2; ++i) {
    gload_lds16(A + (bm0 + i * 32 + srow) * DIM + scol, &As[0][(i * 32 + srow) * 64 + scol]);
    gload_lds16(Bt + (bn0 + i * 32 + srow) * DIM + scol, &Bs[0][(i * 32 + srow) * 64 + scol]);
  }
  __syncthreads();

  for (int kt = 0; kt < 16; ++kt) {
    const int cur = kt & 1;
    if (kt < 15) {
#pragma unroll
      for (int i = 0; i < 2; ++i) {
        gload_lds16(A + (bm0 + i * 32 + srow) * DIM + (kt + 1) * 64 + scol,
                    &As[cur ^ 1][(i * 32 + srow) * 64 + scol]);
        gload_lds16(Bt + (bn0 + i * 32 + srow) * DIM + (kt + 1) * 64 + scol,
                    &Bs[cur ^ 1][(i * 32 + srow) * 64 + scol]);
      }
    }
    bf16x8 a[2][2], b[2][2];
#pragma unroll
    for (int m = 0; m < 2; ++m)
#pragma unroll
      for (int kk = 0; kk < 2; ++kk)
        a[m][kk] = *reinterpret_cast<const bf16x8*>(
            &As[cur][(wm * 32 + m * 16 + lr) * 64 + kk * 32 + lg * 8]);
#pragma unroll
    for (int n = 0; n < 2; ++n)
#pragma unroll
      for (int kk = 0; kk < 2; ++kk)
        b[n][kk] = *reinterpret_cast<const bf16x8*>(
            &Bs[cur][(wn * 32 + n * 16 + lr) * 64 + kk * 32 + lg * 8]);
#pragma unroll
    for (int m = 0; m < 2; ++m)
#pragma unroll
      for (int n = 0; n < 2; ++n)
#pragma unroll
        for (int kk = 0; kk < 2; ++kk)
          acc[m][n] = __builtin_amdgcn_mfma_f32_16x16x32_bf16(a[m][kk], b[n][kk],
                                                              acc[m][n], 0, 0, 0);
    __syncthreads();
  }

#pragma unroll
  for (int m = 0; m < 2; ++m)
#pragma unroll
    for (int n = 0; n < 2; ++n) {
      int col = bn0 + wn * 32 + n * 16 + lr;
      float bv = bias[col];
#pragma unroll
      for (int r = 0; r < 4; ++r) {
        int row = bm0 + wm * 32 + m * 16 + lg * 4 + r;
        float val = acc[m][n][r] + bv;
        if (OUT_F32)
          reinterpret_cast<float*>(out)[(size_t)row * DIM + col] = val;
        else
          reinterpret_cast<bf16_t*>(out)[(size_t)row * DIM + col] = f2bf(val);
      }
    }
}

// ---------------- column sums of V ----------------
__global__ void sumv_kernel(const bf16_t* __restrict__ v, float* __restrict__ sumv) {
  int chunk = blockIdx.x >> 2;                   // 64 chunks of 32 rows
  int d = (blockIdx.x & 3) * 256 + threadIdx.x;
  float acc = 0.f;
  int s0 = chunk * 32;
  for (int s = s0; s < s0 + 32; ++s) acc += bf2f(v[s * DIM + d]);
  atomicAdd(&sumv[d], acc);
}

// ---------------- attn: chunk-max threshold top-k + sparse softmax + V gather --------
// block = 256 threads (4 waves), 64 q-rows x one head. grid (32, 16).
__global__ __launch_bounds__(256) void attn_kernel(const bf16_t* __restrict__ q,
                                                   const bf16_t* __restrict__ k,
                                                   const bf16_t* __restrict__ v,
                                                   const float* __restrict__ sumv,
                                                   bf16_t* __restrict__ op) {
  __shared__ __align__(16) bf16_t Ks[2][64 * 64];  // 16 KB dbuf
  __shared__ float CM[64 * 33];                    // chunk maxima; reused for weights/idx
  __shared__ float Tsh[64];
  __shared__ float zsh[64];
  __shared__ int   cnt[64];
  __shared__ float cval[64 * CST];
  __shared__ int   cidx[64 * CST];

  const int t = threadIdx.x;
  const int qt = blockIdx.x, h = blockIdx.y;
  const int w = t >> 6, lane = t & 63, lr = lane & 15, lg = lane >> 4;
  const int srow = t >> 3, scol = (t & 7) * 8;

  // Q fragments held in registers for both passes (wave w owns rows w*16..+15)
  bf16x8 aq[2];
#pragma unroll
  for (int kk = 0; kk < 2; ++kk)
    aq[kk] = *reinterpret_cast<const bf16x8*>(
        q + (size_t)(qt * 64 + w * 16 + lr) * DIM + h * HDIM + kk * 32 + lg * 8);

  // ---- pass 1: per-(row,chunk) maxima ----
#pragma unroll
  for (int i = 0; i < 2; ++i)
    gload_lds16(k + (size_t)(i * 32 + srow) * DIM + h * HDIM + scol,
                &Ks[0][(i * 32 + srow) * 64 + scol]);
  __syncthreads();

  for (int kc = 0; kc < 32; ++kc) {
    const int cur = kc & 1;
    if (kc < 31) {
#pragma unroll
      for (int i = 0; i < 2; ++i)
        gload_lds16(k + (size_t)((kc + 1) * 64 + i * 32 + srow) * DIM + h * HDIM + scol,
                    &Ks[cur ^ 1][(i * 32 + srow) * 64 + scol]);
    }
    f32x4 sacc[4];
#pragma unroll
    for (int n = 0; n < 4; ++n) sacc[n] = zero4();
    bf16x8 bk_[4][2];
#pragma unroll
    for (int n = 0; n < 4; ++n)
#pragma unroll
      for (int kk = 0; kk < 2; ++kk)
        bk_[n][kk] = *reinterpret_cast<const bf16x8*>(
            &Ks[cur][(n * 16 + lr) * 64 + kk * 32 + lg * 8]);
#pragma unroll
    for (int n = 0; n < 4; ++n)
#pragma unroll
      for (int kk = 0; kk < 2; ++kk)
        sacc[n] = __builtin_amdgcn_mfma_f32_16x16x32_bf16(aq[kk], bk_[n][kk], sacc[n], 0, 0, 0);
#pragma unroll
    for (int r = 0; r < 4; ++r) {
      float mx = fmaxf(fmaxf(sacc[0][r], sacc[1][r]), fmaxf(sacc[2][r], sacc[3][r]));
#pragma unroll
      for (int off = 1; off < 16; off <<= 1) mx = fmaxf(mx, __shfl_xor(mx, off));
      if (lr == 0) CM[(w * 16 + lg * 4 + r) * 33 + kc] = mx * 0.125f;
    }
    __syncthreads();
  }

  // issue pass-2 prologue staging now; it drains at the next barrier
#pragma unroll
  for (int i = 0; i < 2; ++i)
    gload_lds16(k + (size_t)(i * 32 + srow) * DIM + h * HDIM + scol,
                &Ks[0][(i * 32 + srow) * 64 + scol]);

  // T = 16th-largest chunk-max (guaranteed superset threshold); zero counters
  if (t < 64) {
    float vv[32];
#pragma unroll
    for (int c = 0; c < 32; ++c) vv[c] = CM[t * 33 + c];
    float T = -1e30f;
#pragma unroll
    for (int it = 0; it < TOPK; ++it) {
      float mx = vv[0];
#pragma unroll
      for (int c = 1; c < 32; ++c) mx = fmaxf(mx, vv[c]);
      T = mx;
      bool done = false;
#pragma unroll
      for (int c = 0; c < 32; ++c)
        if (!done && vv[c] == mx) { vv[c] = -1e30f; done = true; }
    }
    Tsh[t] = T;
    cnt[t] = 0;
  }
  __syncthreads();

  // ---- pass 2: recompute scores, collect vals >= T[row] ----
  for (int kc = 0; kc < 32; ++kc) {
    const int cur = kc & 1;
    if (kc < 31) {
#pragma unroll
      for (int i = 0; i < 2; ++i)
        gload_lds16(k + (size_t)((kc + 1) * 64 + i * 32 + srow) * DIM + h * HDIM + scol,
                    &Ks[cur ^ 1][(i * 32 + srow) * 64 + scol]);
    }
    f32x4 sacc[4];
#pragma unroll
    for (int n = 0; n < 4; ++n) sacc[n] = zero4();
    bf16x8 bk_[4][2];
#pragma unroll
    for (int n = 0; n < 4; ++n)
#pragma unroll
      for (int kk = 0; kk < 2; ++kk)
        bk_[n][kk] = *reinterpret_cast<const bf16x8*>(
            &Ks[cur][(n * 16 + lr) * 64 + kk * 32 + lg * 8]);
#pragma unroll
    for (int n = 0; n < 4; ++n)
#pragma unroll
      for (int kk = 0; kk < 2; ++kk)
        sacc[n] = __builtin_amdgcn_mfma_f32_16x16x32_bf16(aq[kk], bk_[n][kk], sacc[n], 0, 0, 0);
#pragma unroll
    for (int n = 0; n < 4; ++n)
#pragma unroll
      for (int r = 0; r < 4; ++r) {
        float val = sacc[n][r] * 0.125f;
        int row = w * 16 + lg * 4 + r;
        if (val >= Tsh[row]) {
          int p = atomicAdd(&cnt[row], 1);
          if (p < CAP) {
            cval[row * CST + p] = val;
            cidx[row * CST + p] = kc * 64 + n * 16 + lr;
          }
        }
      }
    __syncthreads();
  }

  // ---- pass 3: exact top-16 among candidates (tie: lower index), weights ----
  if (t < 64) {
    int n = cnt[t]; if (n > CAP) n = CAP;
    float Zexp = 0.f;
    for (int sel = 0; sel < TOPK; ++sel) {
      float best = -1e30f; int bidx = 0x7fffffff; int bp = 0;
      for (int p = 0; p < n; ++p) {
        float vv = cval[t * CST + p];
        int ii = cidx[t * CST + p];
        bool better = (vv > best) || (vv == best && ii < bidx);
        if (better) { best = vv; bidx = ii; bp = p; }
      }
      cval[t * CST + bp] = -1e30f;
      float e = expf(best);
      Zexp += e;
      CM[t * 33 + sel] = e - 1.f;                 // weight
      CM[t * 33 + 16 + sel] = __int_as_float(bidx);  // index
    }
    zsh[t] = 2032.f + Zexp;  // (2048-16) zeros contribute exp(0)=1
  }
  __syncthreads();

  // ---- pass 4: out = (sumv + sum_j w_j * v[idx_j]) / Z ----
  {
    const int row = t >> 2;
    const int dbase = h * HDIM + (t & 3) * 16;
    float oacc[16];
    const float4* sp = reinterpret_cast<const float4*>(sumv + dbase);
#pragma unroll
    for (int u = 0; u < 4; ++u) {
      float4 s4 = sp[u];
      oacc[u * 4 + 0] = s4.x; oacc[u * 4 + 1] = s4.y;
      oacc[u * 4 + 2] = s4.z; oacc[u * 4 + 3] = s4.w;
    }
    float invZ = 1.f / zsh[row];
#pragma unroll
    for (int j = 0; j < TOPK; ++j) {
      float wj = CM[row * 33 + j];
      int kidx = __float_as_int(CM[row * 33 + 16 + j]);
      const bf16x8* vp = reinterpret_cast<const bf16x8*>(v + (size_t)kidx * DIM + dbase);
      bf16x8 v0 = vp[0], v1 = vp[1];
#pragma unroll
      for (int e = 0; e < 8; ++e) {
        oacc[e] += wj * bf2f((bf16_t)v0[e]);
        oacc[8 + e] += wj * bf2f((bf16_t)v1[e]);
      }
    }
    bf16x8 o0, o1;
#pragma unroll
    for (int e = 0; e < 8; ++e) {
      o0[e] = (short)f2bf(oacc[e] * invZ);
      o1[e] = (short)f2bf(oacc[8 + e] * invZ);
    }
    bf16_t* orow = op + (size_t)(qt * 64 + row) * DIM + dbase;
    *reinterpret_cast<bf16x8*>(orow) = o0;
    *reinterpret_cast<bf16x8*>(orow + 8) = o1;
  }
}

extern "C" void kernel_launch(void* const* d_in, const int* in_sizes, int n_in,
                              void* d_out, int out_size, void* d_ws, size_t ws_size,
                              hipStream_t stream) {
  const float* x  = (const float*)d_in[0];
  const float* Wq = (const float*)d_in[1];
  const float* bq = (const float*)d_in[2];
  const float* Wk = (const float*)d_in[3];
  const float* bk = (const float*)d_in[4];
  const float* Wv = (const float*)d_in[5];
  const float* bv = (const float*)d_in[6];
  const float* Wo = (const float*)d_in[7];
  const float* bo = (const float*)d_in[8];
  float* out = (float*)d_out;

  char* ws = (char*)d_ws;
  bf16_t* xb   = (bf16_t*)(ws + (size_t)(0)  * (1 << 20));
  bf16_t* WqT  = (bf16_t*)(ws + (size_t)(4)  * (1 << 20));
  bf16_t* WkT  = (bf16_t*)(ws + (size_t)(6)  * (1 << 20));
  bf16_t* WvT  = (bf16_t*)(ws + (size_t)(8)  * (1 << 20));
  bf16_t* WoT  = (bf16_t*)(ws + (size_t)(10) * (1 << 20));
  bf16_t* qb   = (bf16_t*)(ws + (size_t)(12) * (1 << 20));
  bf16_t* kb   = (bf16_t*)(ws + (size_t)(16) * (1 << 20));
  bf16_t* vb   = (bf16_t*)(ws + (size_t)(20) * (1 << 20));
  bf16_t* opb  = (bf16_t*)(ws + (size_t)(24) * (1 << 20));
  float*  sumv = (float*) (ws + (size_t)(28) * (1 << 20));

  cast_x_kernel<<<2048, 256, 0, stream>>>(x, xb);
  transpose_cast4<<<dim3(32, 32, 4), dim3(32, 8), 0, stream>>>(Wq, Wk, Wv, Wo,
                                                               WqT, WkT, WvT, WoT);

  // fused Q,K,V projections: grid.x = 3*16
  gemm64<0><<<dim3(48, 32), 256, 0, stream>>>(xb, WqT, WkT, WvT, bq, bk, bv,
                                              (void*)qb, (void*)kb, (void*)vb);

  hipMemsetAsync(sumv, 0, DIM * sizeof(float), stream);
  sumv_kernel<<<256, 256, 0, stream>>>(vb, sumv);

  attn_kernel<<<dim3(SEQ / 64, NH), 256, 0, stream>>>(qb, kb, vb, sumv, opb);

  gemm64<1><<<dim3(16, 32), 256, 0, stream>>>(opb, WoT, WoT, WoT, bo, bo, bo,
                                              (void*)out, (void*)out, (void*)out);
}

// Round 3
// 287.591 us; speedup vs baseline: 2.4709x; 1.0826x over previous
//
#include <hip/hip_runtime.h>
#include <stdint.h>

constexpr int SEQ  = 2048;
constexpr int DIM  = 1024;
constexpr int NH   = 16;
constexpr int HDIM = 64;
constexpr int TOPK = 16;
constexpr int CAP  = 96;   // candidate buffer per row (expected fill ~32)
constexpr int CST  = 97;   // padded stride: bank = (row + p) % 32 -> conflict-free scans

typedef unsigned short bf16_t;
typedef __attribute__((ext_vector_type(8))) short bf16x8;
typedef __attribute__((ext_vector_type(4))) float f32x4;

// T2 XOR swizzle: element-column permutation within a 64-elem (128 B) row.
// Applied to BOTH the global-load source column (LDS dest stays linear, m104/m173)
// and the ds_read address (row base is always a multiple of 8, so row&7 == lr&7).
__device__ __forceinline__ int swzc(int col, int row) { return col ^ ((row & 7) << 3); }

__device__ __forceinline__ float bf2f(bf16_t b) {
  return __uint_as_float(((unsigned)b) << 16);
}
__device__ __forceinline__ bf16_t f2bf(float f) {
  unsigned u = __float_as_uint(f);
  unsigned r = u + 0x7fffu + ((u >> 16) & 1u);
  return (bf16_t)(r >> 16);
}
__device__ __forceinline__ f32x4 zero4() {
  f32x4 z; z[0] = 0.f; z[1] = 0.f; z[2] = 0.f; z[3] = 0.f; return z;
}
__device__ __forceinline__ void gload_lds16(const bf16_t* g, bf16_t* l) {
  __builtin_amdgcn_global_load_lds(
      (const __attribute__((address_space(1))) void*)g,
      (__attribute__((address_space(3))) void*)l, 16, 0, 0);
}

// ---------------- cast x (f32 -> bf16) ----------------
__global__ void cast_x_kernel(const float* __restrict__ x, bf16_t* __restrict__ xb) {
  int i = (blockIdx.x * 256 + threadIdx.x) * 4;
  float4 v = *reinterpret_cast<const float4*>(x + i);
  ushort4 o;
  o.x = f2bf(v.x); o.y = f2bf(v.y); o.z = f2bf(v.z); o.w = f2bf(v.w);
  *reinterpret_cast<ushort4*>(xb + i) = o;
}

// ---------------- transpose + cast 4 weights in one launch ----------------
__global__ void transpose_cast4(const float* __restrict__ W0, const float* __restrict__ W1,
                                const float* __restrict__ W2, const float* __restrict__ W3,
                                bf16_t* __restrict__ T0, bf16_t* __restrict__ T1,
                                bf16_t* __restrict__ T2, bf16_t* __restrict__ T3) {
  const int z = blockIdx.z;
  const float* W = (z == 0) ? W0 : (z == 1) ? W1 : (z == 2) ? W2 : W3;
  bf16_t* WT = (z == 0) ? T0 : (z == 1) ? T1 : (z == 2) ? T2 : T3;
  __shared__ float tile[32][33];
  int tx = threadIdx.x, ty = threadIdx.y;
  int bx = blockIdx.x * 32, by = blockIdx.y * 32;
#pragma unroll
  for (int i = 0; i < 4; ++i)
    tile[ty + i * 8][tx] = W[(by + ty + i * 8) * DIM + bx + tx];
  __syncthreads();
#pragma unroll
  for (int i = 0; i < 4; ++i)
    WT[(bx + ty + i * 8) * DIM + by + tx] = f2bf(tile[tx][ty + i * 8]);
}

// ---------------- GEMM 64x64 tile, BK=64, dbuf single-barrier, swizzled LDS ------
// C[M=2048][N] = A[2048][1024] @ Bt[N][1024]^T + bias.  4 waves, wave tile 32x32.
// grid.x = nmat*16 (which = blockIdx.x>>4 selects Bt/bias/out), grid.y = 32.
template <int OUT_F32>
__global__ __launch_bounds__(256) void gemm64(const bf16_t* __restrict__ A,
                                              const bf16_t* __restrict__ B0,
                                              const bf16_t* __restrict__ B1,
                                              const bf16_t* __restrict__ B2,
                                              const float* __restrict__ c0,
                                              const float* __restrict__ c1,
                                              const float* __restrict__ c2,
                                              void* __restrict__ o0,
                                              void* __restrict__ o1,
                                              void* __restrict__ o2) {
  __shared__ __align__(16) bf16_t As[2][64 * 64];
  __shared__ __align__(16) bf16_t Bs[2][64 * 64];
  const int t = threadIdx.x;
  const int which = blockIdx.x >> 4;
  const bf16_t* Bt = (which == 0) ? B0 : (which == 1) ? B1 : B2;
  const float* bias = (which == 0) ? c0 : (which == 1) ? c1 : c2;
  void* out = (which == 0) ? o0 : (which == 1) ? o1 : o2;
  const int bm0 = blockIdx.y * 64, bn0 = (blockIdx.x & 15) * 64;
  const int w = t >> 6, lane = t & 63, lr = lane & 15, lg = lane >> 4;
  const int wm = w >> 1, wn = w & 1;
  const int srow = t >> 3;
  const int scol = swzc((t & 7) * 8, srow);   // pre-swizzled source column
  const int ldst = srow * 64 + (t & 7) * 8;   // linear LDS dest (elem)
  const int rsw = (lr & 7) << 3;              // read-side swizzle

  f32x4 acc[2][2];
#pragma unroll
  for (int m = 0; m < 2; ++m)
#pragma unroll
    for (int n = 0; n < 2; ++n) acc[m][n] = zero4();

#pragma unroll
  for (int i = 0; i < 2; ++i) {
    gload_lds16(A + (bm0 + i * 32 + srow) * DIM + scol, &As[0][i * 32 * 64 + ldst]);
    gload_lds16(Bt + (bn0 + i * 32 + srow) * DIM + scol, &Bs[0][i * 32 * 64 + ldst]);
  }
  __syncthreads();

  for (int kt = 0; kt < 16; ++kt) {
    const int cur = kt & 1;
    if (kt < 15) {
#pragma unroll
      for (int i = 0; i < 2; ++i) {
        gload_lds16(A + (bm0 + i * 32 + srow) * DIM + (kt + 1) * 64 + scol,
                    &As[cur ^ 1][i * 32 * 64 + ldst]);
        gload_lds16(Bt + (bn0 + i * 32 + srow) * DIM + (kt + 1) * 64 + scol,
                    &Bs[cur ^ 1][i * 32 * 64 + ldst]);
      }
    }
    bf16x8 a[2][2], b[2][2];
#pragma unroll
    for (int m = 0; m < 2; ++m)
#pragma unroll
      for (int kk = 0; kk < 2; ++kk)
        a[m][kk] = *reinterpret_cast<const bf16x8*>(
            &As[cur][(wm * 32 + m * 16 + lr) * 64 + ((kk * 32 + lg * 8) ^ rsw)]);
#pragma unroll
    for (int n = 0; n < 2; ++n)
#pragma unroll
      for (int kk = 0; kk < 2; ++kk)
        b[n][kk] = *reinterpret_cast<const bf16x8*>(
            &Bs[cur][(wn * 32 + n * 16 + lr) * 64 + ((kk * 32 + lg * 8) ^ rsw)]);
#pragma unroll
    for (int m = 0; m < 2; ++m)
#pragma unroll
      for (int n = 0; n < 2; ++n)
#pragma unroll
        for (int kk = 0; kk < 2; ++kk)
          acc[m][n] = __builtin_amdgcn_mfma_f32_16x16x32_bf16(a[m][kk], b[n][kk],
                                                              acc[m][n], 0, 0, 0);
    __syncthreads();
  }

#pragma unroll
  for (int m = 0; m < 2; ++m)
#pragma unroll
    for (int n = 0; n < 2; ++n) {
      int col = bn0 + wn * 32 + n * 16 + lr;
      float bv = bias[col];
#pragma unroll
      for (int r = 0; r < 4; ++r) {
        int row = bm0 + wm * 32 + m * 16 + lg * 4 + r;
        float val = acc[m][n][r] + bv;
        if (OUT_F32)
          reinterpret_cast<float*>(out)[(size_t)row * DIM + col] = val;
        else
          reinterpret_cast<bf16_t*>(out)[(size_t)row * DIM + col] = f2bf(val);
      }
    }
}

// ---------------- column sums of V ----------------
__global__ void sumv_kernel(const bf16_t* __restrict__ v, float* __restrict__ sumv) {
  int chunk = blockIdx.x >> 2;                   // 64 chunks of 32 rows
  int d = (blockIdx.x & 3) * 256 + threadIdx.x;
  float acc = 0.f;
  int s0 = chunk * 32;
  for (int s = s0; s < s0 + 32; ++s) acc += bf2f(v[s * DIM + d]);
  atomicAdd(&sumv[d], acc);
}

// ---------------- attn: chunk-max threshold top-k + sparse softmax + V gather --------
// block = 256 threads (4 waves), 64 q-rows x one head. grid (32, 16).
__global__ __launch_bounds__(256) void attn_kernel(const bf16_t* __restrict__ q,
                                                   const bf16_t* __restrict__ k,
                                                   const bf16_t* __restrict__ v,
                                                   const float* __restrict__ sumv,
                                                   bf16_t* __restrict__ op) {
  __shared__ __align__(16) bf16_t Ks[2][64 * 64];  // 16 KB dbuf
  __shared__ float CM[64 * 33];                    // chunk maxima; reused for weights/idx
  __shared__ float Tsh[64];
  __shared__ float zsh[64];
  __shared__ int   cnt[64];
  __shared__ float cval[64 * CST];
  __shared__ int   cidx[64 * CST];

  const int t = threadIdx.x;
  const int qt = blockIdx.x, h = blockIdx.y;
  const int w = t >> 6, lane = t & 63, lr = lane & 15, lg = lane >> 4;
  const int srow = t >> 3;
  const int scol = swzc((t & 7) * 8, srow);   // pre-swizzled source column
  const int ldst = srow * 64 + (t & 7) * 8;   // linear LDS dest (elem)
  const int rsw = (lr & 7) << 3;              // read-side swizzle

  // Q fragments held in registers for both passes (wave w owns rows w*16..+15)
  bf16x8 aq[2];
#pragma unroll
  for (int kk = 0; kk < 2; ++kk)
    aq[kk] = *reinterpret_cast<const bf16x8*>(
        q + (size_t)(qt * 64 + w * 16 + lr) * DIM + h * HDIM + kk * 32 + lg * 8);

  // ---- pass 1: per-(row,chunk) maxima ----
#pragma unroll
  for (int i = 0; i < 2; ++i)
    gload_lds16(k + (size_t)(i * 32 + srow) * DIM + h * HDIM + scol,
                &Ks[0][i * 32 * 64 + ldst]);
  __syncthreads();

  for (int kc = 0; kc < 32; ++kc) {
    const int cur = kc & 1;
    if (kc < 31) {
#pragma unroll
      for (int i = 0; i < 2; ++i)
        gload_lds16(k + (size_t)((kc + 1) * 64 + i * 32 + srow) * DIM + h * HDIM + scol,
                    &Ks[cur ^ 1][i * 32 * 64 + ldst]);
    }
    f32x4 sacc[4];
#pragma unroll
    for (int n = 0; n < 4; ++n) sacc[n] = zero4();
    bf16x8 bk_[4][2];
#pragma unroll
    for (int n = 0; n < 4; ++n)
#pragma unroll
      for (int kk = 0; kk < 2; ++kk)
        bk_[n][kk] = *reinterpret_cast<const bf16x8*>(
            &Ks[cur][(n * 16 + lr) * 64 + ((kk * 32 + lg * 8) ^ rsw)]);
#pragma unroll
    for (int n = 0; n < 4; ++n)
#pragma unroll
      for (int kk = 0; kk < 2; ++kk)
        sacc[n] = __builtin_amdgcn_mfma_f32_16x16x32_bf16(aq[kk], bk_[n][kk], sacc[n], 0, 0, 0);
#pragma unroll
    for (int r = 0; r < 4; ++r) {
      float mx = fmaxf(fmaxf(sacc[0][r], sacc[1][r]), fmaxf(sacc[2][r], sacc[3][r]));
#pragma unroll
      for (int off = 1; off < 16; off <<= 1) mx = fmaxf(mx, __shfl_xor(mx, off));
      if (lr == 0) CM[(w * 16 + lg * 4 + r) * 33 + kc] = mx * 0.125f;
    }
    __syncthreads();
  }

  // issue pass-2 prologue staging now; it drains at the next barrier
#pragma unroll
  for (int i = 0; i < 2; ++i)
    gload_lds16(k + (size_t)(i * 32 + srow) * DIM + h * HDIM + scol,
                &Ks[0][i * 32 * 64 + ldst]);

  // T = 16th-largest chunk-max (guaranteed superset threshold); zero counters
  if (t < 64) {
    float vv[32];
#pragma unroll
    for (int c = 0; c < 32; ++c) vv[c] = CM[t * 33 + c];
    float T = -1e30f;
#pragma unroll
    for (int it = 0; it < TOPK; ++it) {
      float mx = vv[0];
#pragma unroll
      for (int c = 1; c < 32; ++c) mx = fmaxf(mx, vv[c]);
      T = mx;
      bool done = false;
#pragma unroll
      for (int c = 0; c < 32; ++c)
        if (!done && vv[c] == mx) { vv[c] = -1e30f; done = true; }
    }
    Tsh[t] = T;
    cnt[t] = 0;
  }
  __syncthreads();

  // hoist per-lane thresholds (4 rows per lane: r=0..3)
  float Treg[4];
#pragma unroll
  for (int r = 0; r < 4; ++r) Treg[r] = Tsh[w * 16 + lg * 4 + r];

  // ---- pass 2: recompute scores, collect vals >= T ----
  for (int kc = 0; kc < 32; ++kc) {
    const int cur = kc & 1;
    if (kc < 31) {
#pragma unroll
      for (int i = 0; i < 2; ++i)
        gload_lds16(k + (size_t)((kc + 1) * 64 + i * 32 + srow) * DIM + h * HDIM + scol,
                    &Ks[cur ^ 1][i * 32 * 64 + ldst]);
    }
    f32x4 sacc[4];
#pragma unroll
    for (int n = 0; n < 4; ++n) sacc[n] = zero4();
    bf16x8 bk_[4][2];
#pragma unroll
    for (int n = 0; n < 4; ++n)
#pragma unroll
      for (int kk = 0; kk < 2; ++kk)
        bk_[n][kk] = *reinterpret_cast<const bf16x8*>(
            &Ks[cur][(n * 16 + lr) * 64 + ((kk * 32 + lg * 8) ^ rsw)]);
#pragma unroll
    for (int n = 0; n < 4; ++n)
#pragma unroll
      for (int kk = 0; kk < 2; ++kk)
        sacc[n] = __builtin_amdgcn_mfma_f32_16x16x32_bf16(aq[kk], bk_[n][kk], sacc[n], 0, 0, 0);
#pragma unroll
    for (int n = 0; n < 4; ++n)
#pragma unroll
      for (int r = 0; r < 4; ++r) {
        float val = sacc[n][r] * 0.125f;
        if (val >= Treg[r]) {
          int row = w * 16 + lg * 4 + r;
          int p = atomicAdd(&cnt[row], 1);
          if (p < CAP) {
            cval[row * CST + p] = val;
            cidx[row * CST + p] = kc * 64 + n * 16 + lr;
          }
        }
      }
    __syncthreads();
  }

  // ---- pass 3: exact top-16 among candidates (tie: lower index), weights ----
  if (t < 64) {
    int n = cnt[t]; if (n > CAP) n = CAP;
    float Zexp = 0.f;
    for (int sel = 0; sel < TOPK; ++sel) {
      float best = -1e30f; int bidx = 0x7fffffff; int bp = 0;
      for (int p = 0; p < n; ++p) {
        float vv = cval[t * CST + p];
        int ii = cidx[t * CST + p];
        bool better = (vv > best) || (vv == best && ii < bidx);
        if (better) { best = vv; bidx = ii; bp = p; }
      }
      cval[t * CST + bp] = -1e30f;
      float e = expf(best);
      Zexp += e;
      CM[t * 33 + sel] = e - 1.f;                    // weight
      CM[t * 33 + 16 + sel] = __int_as_float(bidx);  // index
    }
    zsh[t] = 2032.f + Zexp;  // (2048-16) zeros contribute exp(0)=1
  }
  __syncthreads();

  // ---- pass 4: out = (sumv + sum_j w_j * v[idx_j]) / Z ----
  {
    const int row = t >> 2;
    const int dbase = h * HDIM + (t & 3) * 16;
    float oacc[16];
    const float4* sp = reinterpret_cast<const float4*>(sumv + dbase);
#pragma unroll
    for (int u = 0; u < 4; ++u) {
      float4 s4 = sp[u];
      oacc[u * 4 + 0] = s4.x; oacc[u * 4 + 1] = s4.y;
      oacc[u * 4 + 2] = s4.z; oacc[u * 4 + 3] = s4.w;
    }
    float invZ = 1.f / zsh[row];
#pragma unroll
    for (int j = 0; j < TOPK; ++j) {
      float wj = CM[row * 33 + j];
      int kidx = __float_as_int(CM[row * 33 + 16 + j]);
      const bf16x8* vp = reinterpret_cast<const bf16x8*>(v + (size_t)kidx * DIM + dbase);
      bf16x8 v0 = vp[0], v1 = vp[1];
#pragma unroll
      for (int e = 0; e < 8; ++e) {
        oacc[e] += wj * bf2f((bf16_t)v0[e]);
        oacc[8 + e] += wj * bf2f((bf16_t)v1[e]);
      }
    }
    bf16x8 o0, o1;
#pragma unroll
    for (int e = 0; e < 8; ++e) {
      o0[e] = (short)f2bf(oacc[e] * invZ);
      o1[e] = (short)f2bf(oacc[8 + e] * invZ);
    }
    bf16_t* orow = op + (size_t)(qt * 64 + row) * DIM + dbase;
    *reinterpret_cast<bf16x8*>(orow) = o0;
    *reinterpret_cast<bf16x8*>(orow + 8) = o1;
  }
}

extern "C" void kernel_launch(void* const* d_in, const int* in_sizes, int n_in,
                              void* d_out, int out_size, void* d_ws, size_t ws_size,
                              hipStream_t stream) {
  const float* x  = (const float*)d_in[0];
  const float* Wq = (const float*)d_in[1];
  const float* bq = (const float*)d_in[2];
  const float* Wk = (const float*)d_in[3];
  const float* bk = (const float*)d_in[4];
  const float* Wv = (const float*)d_in[5];
  const float* bv = (const float*)d_in[6];
  const float* Wo = (const float*)d_in[7];
  const float* bo = (const float*)d_in[8];
  float* out = (float*)d_out;

  char* ws = (char*)d_ws;
  bf16_t* xb   = (bf16_t*)(ws + (size_t)(0)  * (1 << 20));
  bf16_t* WqT  = (bf16_t*)(ws + (size_t)(4)  * (1 << 20));
  bf16_t* WkT  = (bf16_t*)(ws + (size_t)(6)  * (1 << 20));
  bf16_t* WvT  = (bf16_t*)(ws + (size_t)(8)  * (1 << 20));
  bf16_t* WoT  = (bf16_t*)(ws + (size_t)(10) * (1 << 20));
  bf16_t* qb   = (bf16_t*)(ws + (size_t)(12) * (1 << 20));
  bf16_t* kb   = (bf16_t*)(ws + (size_t)(16) * (1 << 20));
  bf16_t* vb   = (bf16_t*)(ws + (size_t)(20) * (1 << 20));
  bf16_t* opb  = (bf16_t*)(ws + (size_t)(24) * (1 << 20));
  float*  sumv = (float*) (ws + (size_t)(28) * (1 << 20));

  cast_x_kernel<<<2048, 256, 0, stream>>>(x, xb);
  transpose_cast4<<<dim3(32, 32, 4), dim3(32, 8), 0, stream>>>(Wq, Wk, Wv, Wo,
                                                               WqT, WkT, WvT, WoT);

  // fused Q,K,V projections: grid.x = 3*16
  gemm64<0><<<dim3(48, 32), 256, 0, stream>>>(xb, WqT, WkT, WvT, bq, bk, bv,
                                              (void*)qb, (void*)kb, (void*)vb);

  hipMemsetAsync(sumv, 0, DIM * sizeof(float), stream);
  sumv_kernel<<<256, 256, 0, stream>>>(vb, sumv);

  attn_kernel<<<dim3(SEQ / 64, NH), 256, 0, stream>>>(qb, kb, vb, sumv, opb);

  gemm64<1><<<dim3(16, 32), 256, 0, stream>>>(opb, WoT, WoT, WoT, bo, bo, bo,
                                              (void*)out, (void*)out, (void*)out);
}

// Round 4
// 261.733 us; speedup vs baseline: 2.7150x; 1.0988x over previous
//
#include <hip/hip_runtime.h>
#include <stdint.h>

constexpr int SEQ  = 2048;
constexpr int DIM  = 1024;
constexpr int NH   = 16;
constexpr int HDIM = 64;
constexpr int TOPK = 16;
constexpr int CAP  = 96;   // candidate buffer per row (expected fill ~22-40)
constexpr int CST  = 97;   // padded stride

typedef unsigned short bf16_t;
typedef __attribute__((ext_vector_type(8))) short bf16x8;
typedef __attribute__((ext_vector_type(4))) float f32x4;

// T2 XOR swizzle for the GEMM LDS tiles (round-2, kept: conflicts 1.28e7 -> 1.9e5)
__device__ __forceinline__ int swzc(int col, int row) { return col ^ ((row & 7) << 3); }

__device__ __forceinline__ float bf2f(bf16_t b) {
  return __uint_as_float(((unsigned)b) << 16);
}
__device__ __forceinline__ bf16_t f2bf(float f) {
  unsigned u = __float_as_uint(f);
  unsigned r = u + 0x7fffu + ((u >> 16) & 1u);
  return (bf16_t)(r >> 16);
}
__device__ __forceinline__ f32x4 zero4() {
  f32x4 z; z[0] = 0.f; z[1] = 0.f; z[2] = 0.f; z[3] = 0.f; return z;
}
__device__ __forceinline__ void gload_lds16(const bf16_t* g, bf16_t* l) {
  __builtin_amdgcn_global_load_lds(
      (const __attribute__((address_space(1))) void*)g,
      (__attribute__((address_space(3))) void*)l, 16, 0, 0);
}

// ---------------- cast x (f32 -> bf16) ----------------
__global__ void cast_x_kernel(const float* __restrict__ x, bf16_t* __restrict__ xb) {
  int i = (blockIdx.x * 256 + threadIdx.x) * 4;
  float4 v = *reinterpret_cast<const float4*>(x + i);
  ushort4 o;
  o.x = f2bf(v.x); o.y = f2bf(v.y); o.z = f2bf(v.z); o.w = f2bf(v.w);
  *reinterpret_cast<ushort4*>(xb + i) = o;
}

// ---------------- transpose + cast 4 weights in one launch ----------------
__global__ void transpose_cast4(const float* __restrict__ W0, const float* __restrict__ W1,
                                const float* __restrict__ W2, const float* __restrict__ W3,
                                bf16_t* __restrict__ T0, bf16_t* __restrict__ T1,
                                bf16_t* __restrict__ T2, bf16_t* __restrict__ T3) {
  const int z = blockIdx.z;
  const float* W = (z == 0) ? W0 : (z == 1) ? W1 : (z == 2) ? W2 : W3;
  bf16_t* WT = (z == 0) ? T0 : (z == 1) ? T1 : (z == 2) ? T2 : T3;
  __shared__ float tile[32][33];
  int tx = threadIdx.x, ty = threadIdx.y;
  int bx = blockIdx.x * 32, by = blockIdx.y * 32;
#pragma unroll
  for (int i = 0; i < 4; ++i)
    tile[ty + i * 8][tx] = W[(by + ty + i * 8) * DIM + bx + tx];
  __syncthreads();
#pragma unroll
  for (int i = 0; i < 4; ++i)
    WT[(bx + ty + i * 8) * DIM + by + tx] = f2bf(tile[tx][ty + i * 8]);
}

// ---------------- GEMM 64x64 tile, BK=64, dbuf single-barrier, swizzled LDS ------
template <int OUT_F32>
__global__ __launch_bounds__(256) void gemm64(const bf16_t* __restrict__ A,
                                              const bf16_t* __restrict__ B0,
                                              const bf16_t* __restrict__ B1,
                                              const bf16_t* __restrict__ B2,
                                              const float* __restrict__ c0,
                                              const float* __restrict__ c1,
                                              const float* __restrict__ c2,
                                              void* __restrict__ o0,
                                              void* __restrict__ o1,
                                              void* __restrict__ o2) {
  __shared__ __align__(16) bf16_t As[2][64 * 64];
  __shared__ __align__(16) bf16_t Bs[2][64 * 64];
  const int t = threadIdx.x;
  const int which = blockIdx.x >> 4;
  const bf16_t* Bt = (which == 0) ? B0 : (which == 1) ? B1 : B2;
  const float* bias = (which == 0) ? c0 : (which == 1) ? c1 : c2;
  void* out = (which == 0) ? o0 : (which == 1) ? o1 : o2;
  const int bm0 = blockIdx.y * 64, bn0 = (blockIdx.x & 15) * 64;
  const int w = t >> 6, lane = t & 63, lr = lane & 15, lg = lane >> 4;
  const int wm = w >> 1, wn = w & 1;
  const int srow = t >> 3;
  const int scol = swzc((t & 7) * 8, srow);
  const int ldst = srow * 64 + (t & 7) * 8;
  const int rsw = (lr & 7) << 3;

  f32x4 acc[2][2];
#pragma unroll
  for (int m = 0; m < 2; ++m)
#pragma unroll
    for (int n = 0; n < 2; ++n) acc[m][n] = zero4();

#pragma unroll
  for (int i = 0; i < 2; ++i) {
    gload_lds16(A + (bm0 + i * 32 + srow) * DIM + scol, &As[0][i * 32 * 64 + ldst]);
    gload_lds16(Bt + (bn0 + i * 32 + srow) * DIM + scol, &Bs[0][i * 32 * 64 + ldst]);
  }
  __syncthreads();

  for (int kt = 0; kt < 16; ++kt) {
    const int cur = kt & 1;
    if (kt < 15) {
#pragma unroll
      for (int i = 0; i < 2; ++i) {
        gload_lds16(A + (bm0 + i * 32 + srow) * DIM + (kt + 1) * 64 + scol,
                    &As[cur ^ 1][i * 32 * 64 + ldst]);
        gload_lds16(Bt + (bn0 + i * 32 + srow) * DIM + (kt + 1) * 64 + scol,
                    &Bs[cur ^ 1][i * 32 * 64 + ldst]);
      }
    }
    bf16x8 a[2][2], b[2][2];
#pragma unroll
    for (int m = 0; m < 2; ++m)
#pragma unroll
      for (int kk = 0; kk < 2; ++kk)
        a[m][kk] = *reinterpret_cast<const bf16x8*>(
            &As[cur][(wm * 32 + m * 16 + lr) * 64 + ((kk * 32 + lg * 8) ^ rsw)]);
#pragma unroll
    for (int n = 0; n < 2; ++n)
#pragma unroll
      for (int kk = 0; kk < 2; ++kk)
        b[n][kk] = *reinterpret_cast<const bf16x8*>(
            &Bs[cur][(wn * 32 + n * 16 + lr) * 64 + ((kk * 32 + lg * 8) ^ rsw)]);
#pragma unroll
    for (int m = 0; m < 2; ++m)
#pragma unroll
      for (int n = 0; n < 2; ++n)
#pragma unroll
        for (int kk = 0; kk < 2; ++kk)
          acc[m][n] = __builtin_amdgcn_mfma_f32_16x16x32_bf16(a[m][kk], b[n][kk],
                                                              acc[m][n], 0, 0, 0);
    __syncthreads();
  }

#pragma unroll
  for (int m = 0; m < 2; ++m)
#pragma unroll
    for (int n = 0; n < 2; ++n) {
      int col = bn0 + wn * 32 + n * 16 + lr;
      float bv = bias[col];
#pragma unroll
      for (int r = 0; r < 4; ++r) {
        int row = bm0 + wm * 32 + m * 16 + lg * 4 + r;
        float val = acc[m][n][r] + bv;
        if (OUT_F32)
          reinterpret_cast<float*>(out)[(size_t)row * DIM + col] = val;
        else
          reinterpret_cast<bf16_t*>(out)[(size_t)row * DIM + col] = f2bf(val);
      }
    }
}

// ---------------- column sums of V ----------------
__global__ void sumv_kernel(const bf16_t* __restrict__ v, float* __restrict__ sumv) {
  int chunk = blockIdx.x >> 2;
  int d = (blockIdx.x & 3) * 256 + threadIdx.x;
  float acc = 0.f;
  int s0 = chunk * 32;
  for (int s = s0; s < s0 + 32; ++s) acc += bf2f(v[s * DIM + d]);
  atomicAdd(&sumv[d], acc);
}

// ---------------- attn v3: barrier-free K-in-register, wave-private chunks --------
// 256 threads = 4 waves. Each wave: ALL 64 q-rows x 8 private k-chunks.
// K fragments global->register (L2-resident via XCD-aware head mapping). 4 barriers total.
__global__ __launch_bounds__(256) void attn_kernel(const bf16_t* __restrict__ q,
                                                   const bf16_t* __restrict__ k,
                                                   const bf16_t* __restrict__ v,
                                                   const float* __restrict__ sumv,
                                                   bf16_t* __restrict__ op) {
  __shared__ float CM[64 * 33];   // chunk maxima; reused for weights/idx after pass 3
  __shared__ float Tsh[64];
  __shared__ float zsh[64];
  __shared__ int   cnt[64];
  __shared__ float cval[64 * CST];
  __shared__ int   cidx[64 * CST];

  const int t = threadIdx.x;
  // XCD-aware bijective remap (512 blocks / 8 XCDs): 2 heads per XCD -> K,V,Q L2-resident
  const int lin = blockIdx.x;
  const int xcd = lin & 7, ixd = lin >> 3;
  const int h = xcd * 2 + (ixd >> 5), qt = ixd & 31;
  const int w = t >> 6, lane = t & 63, lr = lane & 15, lg = lane >> 4;

  const bf16_t* qp = q + (size_t)(qt * 64) * DIM + h * HDIM;
  const bf16_t* kp = k + h * HDIM;

  // Q fragments: all 64 rows (m blocks), kept in registers for both passes
  bf16x8 aq[4][2];
#pragma unroll
  for (int m = 0; m < 4; ++m)
#pragma unroll
    for (int kk = 0; kk < 2; ++kk)
      aq[m][kk] = *reinterpret_cast<const bf16x8*>(
          qp + (size_t)(m * 16 + lr) * DIM + kk * 32 + lg * 8);

  // ---- pass 1: per-(row,chunk) maxima; wave w owns chunks [w*8, w*8+8) ----
  for (int i = 0; i < 8; ++i) {
    const int kc = w * 8 + i;
    bf16x8 bk_[4][2];
#pragma unroll
    for (int n = 0; n < 4; ++n)
#pragma unroll
      for (int kk = 0; kk < 2; ++kk)
        bk_[n][kk] = *reinterpret_cast<const bf16x8*>(
            kp + (size_t)(kc * 64 + n * 16 + lr) * DIM + kk * 32 + lg * 8);

    f32x4 sacc[4][4];
#pragma unroll
    for (int m = 0; m < 4; ++m)
#pragma unroll
      for (int n = 0; n < 4; ++n) sacc[m][n] = zero4();
#pragma unroll
    for (int m = 0; m < 4; ++m)
#pragma unroll
      for (int n = 0; n < 4; ++n)
#pragma unroll
        for (int kk = 0; kk < 2; ++kk)
          sacc[m][n] = __builtin_amdgcn_mfma_f32_16x16x32_bf16(aq[m][kk], bk_[n][kk],
                                                               sacc[m][n], 0, 0, 0);
    // reduce: 16 independent shuffle chains (m x r), interleaved by scheduler
    float mx[4][4];
#pragma unroll
    for (int m = 0; m < 4; ++m)
#pragma unroll
      for (int r = 0; r < 4; ++r)
        mx[m][r] = fmaxf(fmaxf(sacc[m][0][r], sacc[m][1][r]),
                         fmaxf(sacc[m][2][r], sacc[m][3][r]));
#pragma unroll
    for (int off = 1; off < 16; off <<= 1)
#pragma unroll
      for (int m = 0; m < 4; ++m)
#pragma unroll
        for (int r = 0; r < 4; ++r)
          mx[m][r] = fmaxf(mx[m][r], __shfl_xor(mx[m][r], off));
    if (lr == 0) {
#pragma unroll
      for (int m = 0; m < 4; ++m)
#pragma unroll
        for (int r = 0; r < 4; ++r)
          CM[(m * 16 + lg * 4 + r) * 33 + kc] = mx[m][r] * 0.125f;
    }
  }
  __syncthreads();

  // ---- threshold: T = 16th-largest chunk-max (superset guarantee) ----
  if (t < 64) {
    float vv[32];
#pragma unroll
    for (int c = 0; c < 32; ++c) vv[c] = CM[t * 33 + c];
    float T = -1e30f;
#pragma unroll
    for (int it = 0; it < TOPK; ++it) {
      float m0 = vv[0];
#pragma unroll
      for (int c = 1; c < 32; ++c) m0 = fmaxf(m0, vv[c]);
      T = m0;
      bool done = false;
#pragma unroll
      for (int c = 0; c < 32; ++c)
        if (!done && vv[c] == m0) { vv[c] = -1e30f; done = true; }
    }
    Tsh[t] = T;
    cnt[t] = 0;
  }
  __syncthreads();

  float Treg[4][4];
#pragma unroll
  for (int m = 0; m < 4; ++m)
#pragma unroll
    for (int r = 0; r < 4; ++r) Treg[m][r] = Tsh[m * 16 + lg * 4 + r];

  // ---- pass 2: recompute scores, collect vals >= T ----
  for (int i = 0; i < 8; ++i) {
    const int kc = w * 8 + i;
    bf16x8 bk_[4][2];
#pragma unroll
    for (int n = 0; n < 4; ++n)
#pragma unroll
      for (int kk = 0; kk < 2; ++kk)
        bk_[n][kk] = *reinterpret_cast<const bf16x8*>(
            kp + (size_t)(kc * 64 + n * 16 + lr) * DIM + kk * 32 + lg * 8);

    f32x4 sacc[4][4];
#pragma unroll
    for (int m = 0; m < 4; ++m)
#pragma unroll
      for (int n = 0; n < 4; ++n) sacc[m][n] = zero4();
#pragma unroll
    for (int m = 0; m < 4; ++m)
#pragma unroll
      for (int n = 0; n < 4; ++n)
#pragma unroll
        for (int kk = 0; kk < 2; ++kk)
          sacc[m][n] = __builtin_amdgcn_mfma_f32_16x16x32_bf16(aq[m][kk], bk_[n][kk],
                                                               sacc[m][n], 0, 0, 0);
#pragma unroll
    for (int m = 0; m < 4; ++m)
#pragma unroll
      for (int n = 0; n < 4; ++n)
#pragma unroll
        for (int r = 0; r < 4; ++r) {
          float val = sacc[m][n][r] * 0.125f;
          if (val >= Treg[m][r]) {
            int row = m * 16 + lg * 4 + r;
            int p = atomicAdd(&cnt[row], 1);
            if (p < CAP) {
              cval[row * CST + p] = val;
              cidx[row * CST + p] = kc * 64 + n * 16 + lr;
            }
          }
        }
  }
  __syncthreads();

  // ---- pass 3: exact top-16 among candidates (tie: lower index), weights ----
  if (t < 64) {
    int nc = cnt[t]; if (nc > CAP) nc = CAP;
    float Zexp = 0.f;
    for (int sel = 0; sel < TOPK; ++sel) {
      float best = -1e30f; int bidx = 0x7fffffff; int bp = 0;
      for (int p = 0; p < nc; ++p) {
        float vv = cval[t * CST + p];
        int ii = cidx[t * CST + p];
        bool better = (vv > best) || (vv == best && ii < bidx);
        if (better) { best = vv; bidx = ii; bp = p; }
      }
      cval[t * CST + bp] = -1e30f;
      float e = expf(best);
      Zexp += e;
      CM[t * 33 + sel] = e - 1.f;
      CM[t * 33 + 16 + sel] = __int_as_float(bidx);
    }
    zsh[t] = 2032.f + Zexp;  // (2048-16) zeros contribute exp(0)=1
  }
  __syncthreads();

  // ---- pass 4: out = (sumv + sum_j w_j * v[idx_j]) / Z ----
  {
    const int row = t >> 2;
    const int dbase = h * HDIM + (t & 3) * 16;
    float oacc[16];
    const float4* sp = reinterpret_cast<const float4*>(sumv + dbase);
#pragma unroll
    for (int u = 0; u < 4; ++u) {
      float4 s4 = sp[u];
      oacc[u * 4 + 0] = s4.x; oacc[u * 4 + 1] = s4.y;
      oacc[u * 4 + 2] = s4.z; oacc[u * 4 + 3] = s4.w;
    }
    float invZ = 1.f / zsh[row];
#pragma unroll
    for (int j = 0; j < TOPK; ++j) {
      float wj = CM[row * 33 + j];
      int kidx = __float_as_int(CM[row * 33 + 16 + j]);
      const bf16x8* vp = reinterpret_cast<const bf16x8*>(v + (size_t)kidx * DIM + dbase);
      bf16x8 v0 = vp[0], v1 = vp[1];
#pragma unroll
      for (int e = 0; e < 8; ++e) {
        oacc[e] += wj * bf2f((bf16_t)v0[e]);
        oacc[8 + e] += wj * bf2f((bf16_t)v1[e]);
      }
    }
    bf16x8 o0, o1;
#pragma unroll
    for (int e = 0; e < 8; ++e) {
      o0[e] = (short)f2bf(oacc[e] * invZ);
      o1[e] = (short)f2bf(oacc[8 + e] * invZ);
    }
    bf16_t* orow = op + (size_t)(qt * 64 + row) * DIM + dbase;
    *reinterpret_cast<bf16x8*>(orow) = o0;
    *reinterpret_cast<bf16x8*>(orow + 8) = o1;
  }
}

extern "C" void kernel_launch(void* const* d_in, const int* in_sizes, int n_in,
                              void* d_out, int out_size, void* d_ws, size_t ws_size,
                              hipStream_t stream) {
  const float* x  = (const float*)d_in[0];
  const float* Wq = (const float*)d_in[1];
  const float* bq = (const float*)d_in[2];
  const float* Wk = (const float*)d_in[3];
  const float* bk = (const float*)d_in[4];
  const float* Wv = (const float*)d_in[5];
  const float* bv = (const float*)d_in[6];
  const float* Wo = (const float*)d_in[7];
  const float* bo = (const float*)d_in[8];
  float* out = (float*)d_out;

  char* ws = (char*)d_ws;
  bf16_t* xb   = (bf16_t*)(ws + (size_t)(0)  * (1 << 20));
  bf16_t* WqT  = (bf16_t*)(ws + (size_t)(4)  * (1 << 20));
  bf16_t* WkT  = (bf16_t*)(ws + (size_t)(6)  * (1 << 20));
  bf16_t* WvT  = (bf16_t*)(ws + (size_t)(8)  * (1 << 20));
  bf16_t* WoT  = (bf16_t*)(ws + (size_t)(10) * (1 << 20));
  bf16_t* qb   = (bf16_t*)(ws + (size_t)(12) * (1 << 20));
  bf16_t* kb   = (bf16_t*)(ws + (size_t)(16) * (1 << 20));
  bf16_t* vb   = (bf16_t*)(ws + (size_t)(20) * (1 << 20));
  bf16_t* opb  = (bf16_t*)(ws + (size_t)(24) * (1 << 20));
  float*  sumv = (float*) (ws + (size_t)(28) * (1 << 20));

  cast_x_kernel<<<2048, 256, 0, stream>>>(x, xb);
  transpose_cast4<<<dim3(32, 32, 4), dim3(32, 8), 0, stream>>>(Wq, Wk, Wv, Wo,
                                                               WqT, WkT, WvT, WoT);

  gemm64<0><<<dim3(48, 32), 256, 0, stream>>>(xb, WqT, WkT, WvT, bq, bk, bv,
                                              (void*)qb, (void*)kb, (void*)vb);

  hipMemsetAsync(sumv, 0, DIM * sizeof(float), stream);
  sumv_kernel<<<256, 256, 0, stream>>>(vb, sumv);

  attn_kernel<<<512, 256, 0, stream>>>(qb, kb, vb, sumv, opb);

  gemm64<1><<<dim3(16, 32), 256, 0, stream>>>(opb, WoT, WoT, WoT, bo, bo, bo,
                                              (void*)out, (void*)out, (void*)out);
}

// Round 5
// 206.596 us; speedup vs baseline: 3.4396x; 1.2669x over previous
//
#include <hip/hip_runtime.h>
#include <stdint.h>

constexpr int SEQ  = 2048;
constexpr int DIM  = 1024;
constexpr int NH   = 16;
constexpr int HDIM = 64;
constexpr int TOPK = 16;
constexpr int CAP  = 128;  // candidate buffer per row (expected fill ~20-40)
constexpr int CST  = 129;  // padded u64 stride -> rows hit distinct banks

typedef unsigned short bf16_t;
typedef __attribute__((ext_vector_type(8))) short bf16x8;
typedef __attribute__((ext_vector_type(4))) float f32x4;
typedef unsigned long long u64;

// T2 XOR swizzle (kept from round 2: conflicts 1.28e7 -> 1.9e5)
__device__ __forceinline__ int swzc(int col, int row) { return col ^ ((row & 7) << 3); }

__device__ __forceinline__ float bf2f(bf16_t b) {
  return __uint_as_float(((unsigned)b) << 16);
}
__device__ __forceinline__ bf16_t f2bf(float f) {
  unsigned u = __float_as_uint(f);
  unsigned r = u + 0x7fffu + ((u >> 16) & 1u);
  return (bf16_t)(r >> 16);
}
__device__ __forceinline__ f32x4 zero4() {
  f32x4 z; z[0] = 0.f; z[1] = 0.f; z[2] = 0.f; z[3] = 0.f; return z;
}
__device__ __forceinline__ void gload_lds16(const bf16_t* g, bf16_t* l) {
  __builtin_amdgcn_global_load_lds(
      (const __attribute__((address_space(1))) void*)g,
      (__attribute__((address_space(3))) void*)l, 16, 0, 0);
}
// monotone float->uint order transform (total order, matches IEEE for non-NaN)
__device__ __forceinline__ unsigned ordf(float f) {
  unsigned b = __float_as_uint(f);
  return (b & 0x80000000u) ? ~b : (b | 0x80000000u);
}
__device__ __forceinline__ float iordf(unsigned u) {
  unsigned b = (u & 0x80000000u) ? (u ^ 0x80000000u) : ~u;
  return __uint_as_float(b);
}

// ---------------- prep: weight transpose+cast (z<4) and x cast (z==4) ----------------
__global__ void prep_kernel(const float* __restrict__ x, bf16_t* __restrict__ xb,
                            const float* __restrict__ W0, const float* __restrict__ W1,
                            const float* __restrict__ W2, const float* __restrict__ W3,
                            bf16_t* __restrict__ T0, bf16_t* __restrict__ T1,
                            bf16_t* __restrict__ T2, bf16_t* __restrict__ T3) {
  const int z = blockIdx.z;
  if (z == 4) {  // cast x: 1024 blocks x 256 threads x 8 elems = 2.1M
    int bl = blockIdx.y * 32 + blockIdx.x;
    int tt = threadIdx.y * 32 + threadIdx.x;
    int i = (bl * 256 + tt) * 8;
    float4 v0 = *reinterpret_cast<const float4*>(x + i);
    float4 v1 = *reinterpret_cast<const float4*>(x + i + 4);
    bf16x8 o;
    o[0] = (short)f2bf(v0.x); o[1] = (short)f2bf(v0.y);
    o[2] = (short)f2bf(v0.z); o[3] = (short)f2bf(v0.w);
    o[4] = (short)f2bf(v1.x); o[5] = (short)f2bf(v1.y);
    o[6] = (short)f2bf(v1.z); o[7] = (short)f2bf(v1.w);
    *reinterpret_cast<bf16x8*>(xb + i) = o;
    return;
  }
  const float* W = (z == 0) ? W0 : (z == 1) ? W1 : (z == 2) ? W2 : W3;
  bf16_t* WT = (z == 0) ? T0 : (z == 1) ? T1 : (z == 2) ? T2 : T3;
  __shared__ float tile[32][33];
  int tx = threadIdx.x, ty = threadIdx.y;
  int bx = blockIdx.x * 32, by = blockIdx.y * 32;
#pragma unroll
  for (int i = 0; i < 4; ++i)
    tile[ty + i * 8][tx] = W[(by + ty + i * 8) * DIM + bx + tx];
  __syncthreads();
#pragma unroll
  for (int i = 0; i < 4; ++i)
    WT[(bx + ty + i * 8) * DIM + by + tx] = f2bf(tile[tx][ty + i * 8]);
}

// ---------------- GEMM 128x64 tile, BK=64, dbuf, swizzled LDS ------------------------
// C[2048][1024] = A @ Bt^T + bias. 4 waves (2x2), wave tile 64x32, acc[4][2].
// QKV: grid.x = 48 (which = x>>4); DO_SUMV adds V column sums via atomics.
template <int OUT_F32, int DO_SUMV>
__global__ __launch_bounds__(256) void gemm128(const bf16_t* __restrict__ A,
                                               const bf16_t* __restrict__ B0,
                                               const bf16_t* __restrict__ B1,
                                               const bf16_t* __restrict__ B2,
                                               const float* __restrict__ c0,
                                               const float* __restrict__ c1,
                                               const float* __restrict__ c2,
                                               void* __restrict__ o0,
                                               void* __restrict__ o1,
                                               void* __restrict__ o2,
                                               float* __restrict__ sumv) {
  __shared__ __align__(16) bf16_t As[2][128 * 64];
  __shared__ __align__(16) bf16_t Bs[2][64 * 64];
  const int t = threadIdx.x;
  const int which = blockIdx.x >> 4;
  const bf16_t* Bt = (which == 0) ? B0 : (which == 1) ? B1 : B2;
  const float* bias = (which == 0) ? c0 : (which == 1) ? c1 : c2;
  void* out = (which == 0) ? o0 : (which == 1) ? o1 : o2;
  const int bm0 = blockIdx.y * 128, bn0 = (blockIdx.x & 15) * 64;
  const int w = t >> 6, lane = t & 63, lr = lane & 15, lg = lane >> 4;
  const int wm = w >> 1, wn = w & 1;
  const int srow = t >> 3;
  const int scol = swzc((t & 7) * 8, srow);
  const int ldst = srow * 64 + (t & 7) * 8;
  const int rsw = (lr & 7) << 3;

  f32x4 acc[4][2];
#pragma unroll
  for (int m = 0; m < 4; ++m)
#pragma unroll
    for (int n = 0; n < 2; ++n) acc[m][n] = zero4();

#pragma unroll
  for (int i = 0; i < 4; ++i)
    gload_lds16(A + (bm0 + i * 32 + srow) * DIM + scol, &As[0][i * 32 * 64 + ldst]);
#pragma unroll
  for (int i = 0; i < 2; ++i)
    gload_lds16(Bt + (bn0 + i * 32 + srow) * DIM + scol, &Bs[0][i * 32 * 64 + ldst]);
  __syncthreads();

  for (int kt = 0; kt < 16; ++kt) {
    const int cur = kt & 1;
    if (kt < 15) {
#pragma unroll
      for (int i = 0; i < 4; ++i)
        gload_lds16(A + (bm0 + i * 32 + srow) * DIM + (kt + 1) * 64 + scol,
                    &As[cur ^ 1][i * 32 * 64 + ldst]);
#pragma unroll
      for (int i = 0; i < 2; ++i)
        gload_lds16(Bt + (bn0 + i * 32 + srow) * DIM + (kt + 1) * 64 + scol,
                    &Bs[cur ^ 1][i * 32 * 64 + ldst]);
    }
    bf16x8 a[4][2], b[2][2];
#pragma unroll
    for (int m = 0; m < 4; ++m)
#pragma unroll
      for (int kk = 0; kk < 2; ++kk)
        a[m][kk] = *reinterpret_cast<const bf16x8*>(
            &As[cur][(wm * 64 + m * 16 + lr) * 64 + ((kk * 32 + lg * 8) ^ rsw)]);
#pragma unroll
    for (int n = 0; n < 2; ++n)
#pragma unroll
      for (int kk = 0; kk < 2; ++kk)
        b[n][kk] = *reinterpret_cast<const bf16x8*>(
            &Bs[cur][(wn * 32 + n * 16 + lr) * 64 + ((kk * 32 + lg * 8) ^ rsw)]);
#pragma unroll
    for (int m = 0; m < 4; ++m)
#pragma unroll
      for (int n = 0; n < 2; ++n)
#pragma unroll
        for (int kk = 0; kk < 2; ++kk)
          acc[m][n] = __builtin_amdgcn_mfma_f32_16x16x32_bf16(a[m][kk], b[n][kk],
                                                              acc[m][n], 0, 0, 0);
    __syncthreads();
  }

#pragma unroll
  for (int n = 0; n < 2; ++n) {
    int col = bn0 + wn * 32 + n * 16 + lr;
    float bv = bias[col];
    float colsum = 0.f;
#pragma unroll
    for (int m = 0; m < 4; ++m)
#pragma unroll
      for (int r = 0; r < 4; ++r) {
        int row = bm0 + wm * 64 + m * 16 + lg * 4 + r;
        float val = acc[m][n][r] + bv;
        if (OUT_F32) {
          reinterpret_cast<float*>(out)[(size_t)row * DIM + col] = val;
        } else {
          bf16_t rb = f2bf(val);
          reinterpret_cast<bf16_t*>(out)[(size_t)row * DIM + col] = rb;
          if (DO_SUMV) colsum += bf2f(rb);
        }
      }
    if (DO_SUMV && which == 2) atomicAdd(&sumv[col], colsum);
  }
}

// ---------------- attn v4: reg-prefetch K, all-wave-parallel selection ---------------
// 256 threads = 4 waves; 64 q-rows x one head. Wave w owns k-chunks [w*8, w*8+8).
#define LOADK(buf, kc)                                                              \
  do {                                                                              \
    _Pragma("unroll") for (int n_ = 0; n_ < 4; ++n_)                                \
      _Pragma("unroll") for (int k_ = 0; k_ < 2; ++k_)                              \
        kf[buf][n_][k_] = *reinterpret_cast<const bf16x8*>(                         \
            kp + (size_t)((kc) * 64 + n_ * 16 + lr) * DIM + k_ * 32 + lg * 8);      \
  } while (0)

__global__ __launch_bounds__(256, 2) void attn_kernel(const bf16_t* __restrict__ q,
                                                      const bf16_t* __restrict__ k,
                                                      const bf16_t* __restrict__ v,
                                                      const float* __restrict__ sumv,
                                                      bf16_t* __restrict__ op) {
  __shared__ float CM[64 * 33];   // chunk maxima; reused for weights/idx after pass 3
  __shared__ float Tsh[64];
  __shared__ float zsh[64];
  __shared__ int   cnt[64];
  __shared__ u64   ckey[64 * CST];  // packed (ord(val)<<32 | ~idx)

  const int t = threadIdx.x;
  // XCD-aware bijective remap: 2 heads per XCD -> Q/K/V head slices L2-resident
  const int lin = blockIdx.x;
  const int xcd = lin & 7, ixd = lin >> 3;
  const int h = xcd * 2 + (ixd >> 5), qt = ixd & 31;
  const int w = t >> 6, lane = t & 63, lr = lane & 15, lg = lane >> 4;

  const bf16_t* qp = q + (size_t)(qt * 64) * DIM + h * HDIM;
  const bf16_t* kp = k + h * HDIM;

  // Q fragments: all 64 rows, registers for both passes
  bf16x8 aq[4][2];
#pragma unroll
  for (int m = 0; m < 4; ++m)
#pragma unroll
    for (int kk = 0; kk < 2; ++kk)
      aq[m][kk] = *reinterpret_cast<const bf16x8*>(
          qp + (size_t)(m * 16 + lr) * DIM + kk * 32 + lg * 8);

  bf16x8 kf[2][4][2];

  // ---- pass 1: per-(row,chunk) maxima, 1-deep prefetch ----
  LOADK(0, w * 8);
#pragma unroll
  for (int i = 0; i < 8; ++i) {
    if (i < 7) LOADK((i + 1) & 1, w * 8 + i + 1);
    const int cur = i & 1;
    f32x4 sacc[4][4];
#pragma unroll
    for (int m = 0; m < 4; ++m)
#pragma unroll
      for (int n = 0; n < 4; ++n) sacc[m][n] = zero4();
#pragma unroll
    for (int m = 0; m < 4; ++m)
#pragma unroll
      for (int n = 0; n < 4; ++n)
#pragma unroll
        for (int kk = 0; kk < 2; ++kk)
          sacc[m][n] = __builtin_amdgcn_mfma_f32_16x16x32_bf16(aq[m][kk], kf[cur][n][kk],
                                                               sacc[m][n], 0, 0, 0);
    float mx[4][4];
#pragma unroll
    for (int m = 0; m < 4; ++m)
#pragma unroll
      for (int r = 0; r < 4; ++r)
        mx[m][r] = fmaxf(fmaxf(sacc[m][0][r], sacc[m][1][r]),
                         fmaxf(sacc[m][2][r], sacc[m][3][r]));
#pragma unroll
    for (int off = 1; off < 16; off <<= 1)
#pragma unroll
      for (int m = 0; m < 4; ++m)
#pragma unroll
        for (int r = 0; r < 4; ++r)
          mx[m][r] = fmaxf(mx[m][r], __shfl_xor(mx[m][r], off));
    if (lr == 0) {
#pragma unroll
      for (int m = 0; m < 4; ++m)
#pragma unroll
        for (int r = 0; r < 4; ++r)
          CM[(m * 16 + lg * 4 + r) * 33 + (w * 8 + i)] = mx[m][r] * 0.125f;
    }
  }
  LOADK(0, w * 8);  // prefetch pass-2 first tile across the threshold phase
  __syncthreads();

  // ---- threshold: T = 16th-largest chunk-max, 4 lanes per row ----
  {
    const int trow = t >> 2, tsub = t & 3;
    float cmv[8];
#pragma unroll
    for (int c = 0; c < 8; ++c) cmv[c] = CM[trow * 33 + tsub * 8 + c];
    float Tval = -1e30f;
#pragma unroll
    for (int it = 0; it < TOPK; ++it) {
      float lm = cmv[0];
#pragma unroll
      for (int c = 1; c < 8; ++c) lm = fmaxf(lm, cmv[c]);
      float gm = fmaxf(lm, __shfl_xor(lm, 1));
      gm = fmaxf(gm, __shfl_xor(gm, 2));
      u64 b = __ballot(lm == gm);
      int base = lane & ~3;
      int ownsub = __ffsll((b >> base) & 0xFull) - 1;
      if (tsub == ownsub) {
        bool d = false;
#pragma unroll
        for (int c = 0; c < 8; ++c)
          if (!d && cmv[c] == lm) { cmv[c] = -1e30f; d = true; }
      }
      Tval = gm;
    }
    if (tsub == 0) { Tsh[trow] = Tval; cnt[trow] = 0; }
  }
  __syncthreads();

  float Treg[4][4];
#pragma unroll
  for (int m = 0; m < 4; ++m)
#pragma unroll
    for (int r = 0; r < 4; ++r) Treg[m][r] = Tsh[m * 16 + lg * 4 + r];

  // ---- pass 2: recompute scores, collect packed keys >= T ----
#pragma unroll
  for (int i = 0; i < 8; ++i) {
    if (i < 7) LOADK((i + 1) & 1, w * 8 + i + 1);
    const int cur = i & 1;
    const int kc = w * 8 + i;
    f32x4 sacc[4][4];
#pragma unroll
    for (int m = 0; m < 4; ++m)
#pragma unroll
      for (int n = 0; n < 4; ++n) sacc[m][n] = zero4();
#pragma unroll
    for (int m = 0; m < 4; ++m)
#pragma unroll
      for (int n = 0; n < 4; ++n)
#pragma unroll
        for (int kk = 0; kk < 2; ++kk)
          sacc[m][n] = __builtin_amdgcn_mfma_f32_16x16x32_bf16(aq[m][kk], kf[cur][n][kk],
                                                               sacc[m][n], 0, 0, 0);
#pragma unroll
    for (int m = 0; m < 4; ++m)
#pragma unroll
      for (int n = 0; n < 4; ++n)
#pragma unroll
        for (int r = 0; r < 4; ++r) {
          float val = sacc[m][n][r] * 0.125f;
          if (val >= Treg[m][r]) {
            int row = m * 16 + lg * 4 + r;
            int p = atomicAdd(&cnt[row], 1);
            if (p < CAP) {
              unsigned idx = (unsigned)(kc * 64 + n * 16 + lr);
              ckey[row * CST + p] = ((u64)ordf(val) << 32) | (u64)(~idx);
            }
          }
        }
  }
  __syncthreads();

  // ---- pass 3: exact top-16 (u64 max = value order, lower-index tie-break) ----
  {
    const int trow = t >> 2, tsub = t & 3;
    int nc = cnt[trow]; if (nc > CAP) nc = CAP;
    float Zexp = 0.f;
    for (int sel = 0; sel < TOPK; ++sel) {
      u64 lmax = 0ull; int lp = -1;
      for (int p = tsub; p < nc; p += 4) {
        u64 kk2 = ckey[trow * CST + p];
        if (kk2 > lmax) { lmax = kk2; lp = p; }
      }
      u64 o1 = __shfl_xor(lmax, 1);
      u64 g1 = (o1 > lmax) ? o1 : lmax;
      u64 o2 = __shfl_xor(g1, 2);
      u64 gkey = (o2 > g1) ? o2 : g1;
      if (lmax == gkey && lp >= 0) ckey[trow * CST + lp] = 0ull;  // unique keys
      float val = iordf((unsigned)(gkey >> 32));
      int idx = (int)(~(unsigned)(gkey & 0xffffffffull));
      float e = expf(val);
      Zexp += e;
      if (tsub == 0) {
        CM[trow * 33 + sel] = e - 1.f;
        CM[trow * 33 + 16 + sel] = __int_as_float(idx);
      }
    }
    if (tsub == 0) zsh[trow] = 2032.f + Zexp;  // (2048-16) zeros give exp(0)=1
  }
  __syncthreads();

  // ---- pass 4: out = (sumv + sum_j w_j * v[idx_j]) / Z ----
  {
    const int row = t >> 2;
    const int dbase = h * HDIM + (t & 3) * 16;
    float oacc[16];
    const float4* sp = reinterpret_cast<const float4*>(sumv + dbase);
#pragma unroll
    for (int u = 0; u < 4; ++u) {
      float4 s4 = sp[u];
      oacc[u * 4 + 0] = s4.x; oacc[u * 4 + 1] = s4.y;
      oacc[u * 4 + 2] = s4.z; oacc[u * 4 + 3] = s4.w;
    }
    float invZ = 1.f / zsh[row];
#pragma unroll
    for (int j = 0; j < TOPK; ++j) {
      float wj = CM[row * 33 + j];
      int kidx = __float_as_int(CM[row * 33 + 16 + j]);
      const bf16x8* vp = reinterpret_cast<const bf16x8*>(v + (size_t)kidx * DIM + dbase);
      bf16x8 v0 = vp[0], v1 = vp[1];
#pragma unroll
      for (int e = 0; e < 8; ++e) {
        oacc[e] += wj * bf2f((bf16_t)v0[e]);
        oacc[8 + e] += wj * bf2f((bf16_t)v1[e]);
      }
    }
    bf16x8 o0, o1;
#pragma unroll
    for (int e = 0; e < 8; ++e) {
      o0[e] = (short)f2bf(oacc[e] * invZ);
      o1[e] = (short)f2bf(oacc[8 + e] * invZ);
    }
    bf16_t* orow = op + (size_t)(qt * 64 + row) * DIM + dbase;
    *reinterpret_cast<bf16x8*>(orow) = o0;
    *reinterpret_cast<bf16x8*>(orow + 8) = o1;
  }
}

extern "C" void kernel_launch(void* const* d_in, const int* in_sizes, int n_in,
                              void* d_out, int out_size, void* d_ws, size_t ws_size,
                              hipStream_t stream) {
  const float* x  = (const float*)d_in[0];
  const float* Wq = (const float*)d_in[1];
  const float* bq = (const float*)d_in[2];
  const float* Wk = (const float*)d_in[3];
  const float* bk = (const float*)d_in[4];
  const float* Wv = (const float*)d_in[5];
  const float* bv = (const float*)d_in[6];
  const float* Wo = (const float*)d_in[7];
  const float* bo = (const float*)d_in[8];
  float* out = (float*)d_out;

  char* ws = (char*)d_ws;
  bf16_t* xb   = (bf16_t*)(ws + (size_t)(0)  * (1 << 20));
  bf16_t* WqT  = (bf16_t*)(ws + (size_t)(4)  * (1 << 20));
  bf16_t* WkT  = (bf16_t*)(ws + (size_t)(6)  * (1 << 20));
  bf16_t* WvT  = (bf16_t*)(ws + (size_t)(8)  * (1 << 20));
  bf16_t* WoT  = (bf16_t*)(ws + (size_t)(10) * (1 << 20));
  bf16_t* qb   = (bf16_t*)(ws + (size_t)(12) * (1 << 20));
  bf16_t* kb   = (bf16_t*)(ws + (size_t)(16) * (1 << 20));
  bf16_t* vb   = (bf16_t*)(ws + (size_t)(20) * (1 << 20));
  bf16_t* opb  = (bf16_t*)(ws + (size_t)(24) * (1 << 20));
  float*  sumv = (float*) (ws + (size_t)(28) * (1 << 20));

  prep_kernel<<<dim3(32, 32, 5), dim3(32, 8), 0, stream>>>(x, xb, Wq, Wk, Wv, Wo,
                                                           WqT, WkT, WvT, WoT);
  hipMemsetAsync(sumv, 0, DIM * sizeof(float), stream);

  gemm128<0, 1><<<dim3(48, 16), 256, 0, stream>>>(xb, WqT, WkT, WvT, bq, bk, bv,
                                                  (void*)qb, (void*)kb, (void*)vb, sumv);

  attn_kernel<<<512, 256, 0, stream>>>(qb, kb, vb, sumv, opb);

  gemm128<1, 0><<<dim3(16, 16), 256, 0, stream>>>(opb, WoT, WoT, WoT, bo, bo, bo,
                                                  (void*)out, (void*)out, (void*)out, sumv);
}